// Round 17
// baseline (1336.473 us; speedup 1.0000x reference)
//
#include <hip/hip_runtime.h>
#include <math.h>

// MultiViewAggregation — round 17.
// A: row-batched MLP, 2px/384thr, unit = 8 rows x 4 cols (FMA/LDS-read ratio
//    8 -> 10.7; LDS wave-instructions -25%). T14 reg prefetch kept.
// B1/B2: round-14 (T14 prefetch) kernels, unchanged.

#define NPIX 16384

__device__ __forceinline__ float elu_f(float x){ return x > 0.f ? x : (__expf(x) - 1.f); }
__device__ __forceinline__ float gelu_f(float x){ return 0.5f*x*(1.f + erff(x*0.70710678118654752f)); }

__device__ __forceinline__ void fma4(float4& a, float s, const float4 w){
  a.x = fmaf(s, w.x, a.x); a.y = fmaf(s, w.y, a.y);
  a.z = fmaf(s, w.z, a.z); a.w = fmaf(s, w.w, a.w);
}
__device__ __forceinline__ float4 elu4f(float4 a){
  return make_float4(elu_f(a.x), elu_f(a.y), elu_f(a.z), elu_f(a.w));
}

// ===================== Kernel A =====================
#define NTA 384
#define NBA (NPIX/2)

constexpr int AYA   = 0;         // [192][72] = 13824
constexpr int AYB   = 13824;     // [192][72] ; F[192][34] aliases head
constexpr int AWB   = 27648;     // 4096
constexpr int AXL   = 31744;     // [192][8] = 1536
constexpr int ABIAS = 33280;     // 224
constexpr int ATOT  = 33504;     // 134 KB -> 1 block/CU (6 waves)

// 192-row x 64-col layer: unit (rq = t>>4 in [0,24) -> 8 rows, c4 = t&15).
template<int K, int SI, bool DOELU>
__device__ __forceinline__ void mmA64(const float* __restrict__ Xin,
                                      const float* __restrict__ WB,
                                      const float* __restrict__ bias,
                                      float* __restrict__ Yout, int t)
{
  const int rq = t >> 4, c4 = t & 15;
  const int r0 = 8*rq;
  const float4* __restrict__ W4 = (const float4*)WB;
  const float4 b = ((const float4*)bias)[c4];
  float4 a0=b, a1=b, a2=b, a3=b, a4=b, a5=b, a6=b, a7=b;
  #pragma unroll
  for (int k4 = 0; k4 < K/4; ++k4){
    const float4 xa = *(const float4*)(Xin + (r0+0)*SI + 4*k4);
    const float4 xb = *(const float4*)(Xin + (r0+1)*SI + 4*k4);
    const float4 xc = *(const float4*)(Xin + (r0+2)*SI + 4*k4);
    const float4 xd = *(const float4*)(Xin + (r0+3)*SI + 4*k4);
    const float4 xe = *(const float4*)(Xin + (r0+4)*SI + 4*k4);
    const float4 xf = *(const float4*)(Xin + (r0+5)*SI + 4*k4);
    const float4 xg = *(const float4*)(Xin + (r0+6)*SI + 4*k4);
    const float4 xh = *(const float4*)(Xin + (r0+7)*SI + 4*k4);
    const float4 w0 = W4[(4*k4+0)*16 + c4];
    const float4 w1 = W4[(4*k4+1)*16 + c4];
    const float4 w2 = W4[(4*k4+2)*16 + c4];
    const float4 w3 = W4[(4*k4+3)*16 + c4];
    fma4(a0, xa.x, w0); fma4(a0, xa.y, w1); fma4(a0, xa.z, w2); fma4(a0, xa.w, w3);
    fma4(a1, xb.x, w0); fma4(a1, xb.y, w1); fma4(a1, xb.z, w2); fma4(a1, xb.w, w3);
    fma4(a2, xc.x, w0); fma4(a2, xc.y, w1); fma4(a2, xc.z, w2); fma4(a2, xc.w, w3);
    fma4(a3, xd.x, w0); fma4(a3, xd.y, w1); fma4(a3, xd.z, w2); fma4(a3, xd.w, w3);
    fma4(a4, xe.x, w0); fma4(a4, xe.y, w1); fma4(a4, xe.z, w2); fma4(a4, xe.w, w3);
    fma4(a5, xf.x, w0); fma4(a5, xf.y, w1); fma4(a5, xf.z, w2); fma4(a5, xf.w, w3);
    fma4(a6, xg.x, w0); fma4(a6, xg.y, w1); fma4(a6, xg.z, w2); fma4(a6, xg.w, w3);
    fma4(a7, xh.x, w0); fma4(a7, xh.y, w1); fma4(a7, xh.z, w2); fma4(a7, xh.w, w3);
  }
  if (DOELU){
    a0 = elu4f(a0); a1 = elu4f(a1); a2 = elu4f(a2); a3 = elu4f(a3);
    a4 = elu4f(a4); a5 = elu4f(a5); a6 = elu4f(a6); a7 = elu4f(a7);
  }
  *(float4*)(Yout + (r0+0)*72 + 4*c4) = a0;
  *(float4*)(Yout + (r0+1)*72 + 4*c4) = a1;
  *(float4*)(Yout + (r0+2)*72 + 4*c4) = a2;
  *(float4*)(Yout + (r0+3)*72 + 4*c4) = a3;
  *(float4*)(Yout + (r0+4)*72 + 4*c4) = a4;
  *(float4*)(Yout + (r0+5)*72 + 4*c4) = a5;
  *(float4*)(Yout + (r0+6)*72 + 4*c4) = a6;
  *(float4*)(Yout + (r0+7)*72 + 4*c4) = a7;
}

// L4: 192 x 32, unit (rq -> 8 rows, c2 = t&15 -> 2 cols). F stride 34, no act.
__device__ __forceinline__ void mmA32(const float* __restrict__ Xin,
                                      const float* __restrict__ WB,
                                      const float* __restrict__ bias,
                                      float* __restrict__ F, int t)
{
  const int rq = t >> 4, c2 = t & 15;
  const int r0 = 8*rq;
  const float2* __restrict__ W2 = (const float2*)WB;   // [64][16] float2
  const float2 b = ((const float2*)bias)[c2];
  float2 a0=b, a1=b, a2=b, a3=b, a4=b, a5=b, a6=b, a7=b;
  #pragma unroll
  for (int k4 = 0; k4 < 16; ++k4){
    const float4 xa = *(const float4*)(Xin + (r0+0)*72 + 4*k4);
    const float4 xb = *(const float4*)(Xin + (r0+1)*72 + 4*k4);
    const float4 xc = *(const float4*)(Xin + (r0+2)*72 + 4*k4);
    const float4 xd = *(const float4*)(Xin + (r0+3)*72 + 4*k4);
    const float4 xe = *(const float4*)(Xin + (r0+4)*72 + 4*k4);
    const float4 xf = *(const float4*)(Xin + (r0+5)*72 + 4*k4);
    const float4 xg = *(const float4*)(Xin + (r0+6)*72 + 4*k4);
    const float4 xh = *(const float4*)(Xin + (r0+7)*72 + 4*k4);
    #pragma unroll
    for (int i = 0; i < 4; ++i){
      const float2 w = W2[(4*k4+i)*16 + c2];
      const float sa = (i==0)?xa.x:(i==1)?xa.y:(i==2)?xa.z:xa.w;
      const float sb = (i==0)?xb.x:(i==1)?xb.y:(i==2)?xb.z:xb.w;
      const float sc = (i==0)?xc.x:(i==1)?xc.y:(i==2)?xc.z:xc.w;
      const float sd = (i==0)?xd.x:(i==1)?xd.y:(i==2)?xd.z:xd.w;
      const float se = (i==0)?xe.x:(i==1)?xe.y:(i==2)?xe.z:xe.w;
      const float sf = (i==0)?xf.x:(i==1)?xf.y:(i==2)?xf.z:xf.w;
      const float sg = (i==0)?xg.x:(i==1)?xg.y:(i==2)?xg.z:xg.w;
      const float sh = (i==0)?xh.x:(i==1)?xh.y:(i==2)?xh.z:xh.w;
      a0.x = fmaf(sa, w.x, a0.x); a0.y = fmaf(sa, w.y, a0.y);
      a1.x = fmaf(sb, w.x, a1.x); a1.y = fmaf(sb, w.y, a1.y);
      a2.x = fmaf(sc, w.x, a2.x); a2.y = fmaf(sc, w.y, a2.y);
      a3.x = fmaf(sd, w.x, a3.x); a3.y = fmaf(sd, w.y, a3.y);
      a4.x = fmaf(se, w.x, a4.x); a4.y = fmaf(se, w.y, a4.y);
      a5.x = fmaf(sf, w.x, a5.x); a5.y = fmaf(sf, w.y, a5.y);
      a6.x = fmaf(sg, w.x, a6.x); a6.y = fmaf(sg, w.y, a6.y);
      a7.x = fmaf(sh, w.x, a7.x); a7.y = fmaf(sh, w.y, a7.y);
    }
  }
  *(float2*)(F + (r0+0)*34 + 2*c2) = a0;
  *(float2*)(F + (r0+1)*34 + 2*c2) = a1;
  *(float2*)(F + (r0+2)*34 + 2*c2) = a2;
  *(float2*)(F + (r0+3)*34 + 2*c2) = a3;
  *(float2*)(F + (r0+4)*34 + 2*c2) = a4;
  *(float2*)(F + (r0+5)*34 + 2*c2) = a5;
  *(float2*)(F + (r0+6)*34 + 2*c2) = a6;
  *(float2*)(F + (r0+7)*34 + 2*c2) = a7;
}

__global__ __launch_bounds__(NTA)
void mva_phaseA(const float* __restrict__ view_dir, const float* __restrict__ normal,
                const float* __restrict__ DL,
                const float* __restrict__ ln_g, const float* __restrict__ ln_b,
                const float* __restrict__ w1, const float* __restrict__ b1,
                const float* __restrict__ w2, const float* __restrict__ b2,
                const float* __restrict__ w3, const float* __restrict__ b3,
                const float* __restrict__ w4, const float* __restrict__ b4,
                float* __restrict__ feat)
{
  __shared__ __align__(16) float smem[ATOT];
  const int t = threadIdx.x;
  const int bpx0 = blockIdx.x*2;
  float4* WB4 = (float4*)(smem + AWB);
  const float4 zf4 = make_float4(0.f,0.f,0.f,0.f);

  {
    const float4* s = (const float4*)w1;
    for (int i = t; i < 128; i += NTA){
      const int k = i >> 4, c4 = i & 15;
      WB4[i] = (k < 7) ? s[k*16 + c4] : zf4;
    }
    float4* d = (float4*)(smem+ABIAS);
    if (t >= 256 && t < 272)      d[t-256]      = ((const float4*)b1)[t-256];
    else if (t >= 272 && t < 288) d[16 + t-272] = ((const float4*)b2)[t-272];
    else if (t >= 288 && t < 304) d[32 + t-288] = ((const float4*)b3)[t-288];
    else if (t >= 304 && t < 312) d[48 + t-304] = ((const float4*)b4)[t-304];
  }
  if (t < 192){
    const int pl = t / 96, rr = t - pl*96;
    const int sg = rr >> 3, view = rr & 7;
    const int px = bpx0 + pl;
    const float nm0 = normal[px*3+0], nm1 = normal[px*3+1], nm2 = normal[px*3+2];
    const float* vd = view_dir + (px*8 + view)*3;
    const float vd0 = vd[0], vd1 = vd[1], vd2 = vd[2];
    const float* dl = DL + px*84 + sg*7;
    const float d0=dl[0], d1=dl[1], d2=dl[2], d3=dl[3], d4=dl[4], d5=dl[5], d6=dl[6];

    const float DLdotN = d0*nm0 + d1*nm1 + d2*nm2;
    const float hv     = (d0*vd0 + d1*vd1 + d2*vd2 + 1.f)*0.5f;
    const float fres   = exp2f((-5.55472f*hv - 6.98316f)*hv);
    const float VdotN  = vd0*nm0 + vd1*nm1 + vd2*nm2;

    const float x0 = DLdotN, x1 = d3, x2 = d4, x3 = d5, x4 = d6, x5 = fres, x6 = VdotN;
    const float m  = (x0+x1+x2+x3+x4+x5+x6)*(1.f/7.f);
    float q, var = 0.f;
    q = x0-m; var += q*q; q = x1-m; var += q*q; q = x2-m; var += q*q;
    q = x3-m; var += q*q; q = x4-m; var += q*q; q = x5-m; var += q*q;
    q = x6-m; var += q*q;
    const float rs = rsqrtf(var*(1.f/7.f) + 1e-5f);
    float* xl = smem + AXL + t*8;
    xl[0] = (x0-m)*rs*ln_g[0] + ln_b[0];
    xl[1] = (x1-m)*rs*ln_g[1] + ln_b[1];
    xl[2] = (x2-m)*rs*ln_g[2] + ln_b[2];
    xl[3] = (x3-m)*rs*ln_g[3] + ln_b[3];
    xl[4] = (x4-m)*rs*ln_g[4] + ln_b[4];
    xl[5] = (x5-m)*rs*ln_g[5] + ln_b[5];
    xl[6] = (x6-m)*rs*ln_g[6] + ln_b[6];
    xl[7] = 0.f;
  }
  __syncthreads();

  // T14 prefetch w2 (1024 f4 over 384 thr: slots t, t+384, t+768<1024)
  float4 p0 = ((const float4*)w2)[t];
  float4 p1 = ((const float4*)w2)[t + 384];
  float4 p2 = (t < 256) ? ((const float4*)w2)[t + 768] : zf4;
  mmA64<8,8,true>(smem+AXL, smem+AWB, smem+ABIAS+0, smem+AYA, t);
  __syncthreads();
  WB4[t] = p0; WB4[t + 384] = p1; if (t < 256) WB4[t + 768] = p2;
  __syncthreads();

  p0 = ((const float4*)w3)[t];
  p1 = ((const float4*)w3)[t + 384];
  p2 = (t < 256) ? ((const float4*)w3)[t + 768] : zf4;
  mmA64<64,72,true>(smem+AYA, smem+AWB, smem+ABIAS+64, smem+AYB, t);
  __syncthreads();
  WB4[t] = p0; WB4[t + 384] = p1; if (t < 256) WB4[t + 768] = p2;
  __syncthreads();

  p0 = ((const float4*)w4)[t];
  p1 = (t < 128) ? ((const float4*)w4)[t + 384] : zf4;
  mmA64<64,72,true>(smem+AYB, smem+AWB, smem+ABIAS+128, smem+AYA, t);
  __syncthreads();
  WB4[t] = p0; if (t < 128) WB4[t + 384] = p1;
  __syncthreads();

  mmA32(smem+AYA, smem+AWB, smem+ABIAS+192, smem+AYB, t);
  __syncthreads();

  for (int u = t; u < 512; u += NTA){
    const int pl = u >> 8, idx = u & 255;
    const int v = idx >> 5, c = idx & 31;
    float s = 0.f;
    #pragma unroll
    for (int sg = 0; sg < 12; ++sg) s += smem[AYB + (pl*96 + sg*8 + v)*34 + c];
    feat[(size_t)(bpx0 + pl)*256 + idx] = s;
  }
}

// ===================== Shared B machinery (round-14) =====================
#define NTB 512

template<int KK, int CC, int LDWG>
__device__ __forceinline__ void stageW(const float* __restrict__ Wg, int c4off,
                                       float* __restrict__ wbuf, int t)
{
  constexpr int C4 = CC/4;
  constexpr int N4 = KK*C4;
  const float4* __restrict__ s = (const float4*)Wg;
  float4* d = (float4*)wbuf;
  for (int i = t; i < N4; i += NTB){
    const int k = i / C4, c4 = i - k*C4;
    d[i] = s[k*(LDWG/4) + c4off + c4];
  }
}

#define PFSLOT(Wg, KK, CC, LDWG, C4OFF, SLOT, PFV) { \
  const int _i = t + (SLOT)*512; \
  if ((KK)*((CC)/4) > (SLOT)*512 && _i < (KK)*((CC)/4)){ \
    const int _k = _i/((CC)/4), _c = _i - _k*((CC)/4); \
    PFV = ((const float4*)(Wg))[_k*((LDWG)/4) + (C4OFF) + _c]; } }

#define PFLOADG(Wg, KK, CC, LDWG, C4OFF) \
  PFSLOT(Wg,KK,CC,LDWG,C4OFF,0,pf0) PFSLOT(Wg,KK,CC,LDWG,C4OFF,1,pf1) \
  PFSLOT(Wg,KK,CC,LDWG,C4OFF,2,pf2) PFSLOT(Wg,KK,CC,LDWG,C4OFF,3,pf3) \
  PFSLOT(Wg,KK,CC,LDWG,C4OFF,4,pf4) PFSLOT(Wg,KK,CC,LDWG,C4OFF,5,pf5)

#define PFWR(N4, SLOT, PFV) { if ((N4) > (SLOT)*512 && t + (SLOT)*512 < (N4)) WB4[t+(SLOT)*512] = PFV; }
#define PFWRITE(KK, CC) { \
  PFWR((KK)*((CC)/4),0,pf0) PFWR((KK)*((CC)/4),1,pf1) PFWR((KK)*((CC)/4),2,pf2) \
  PFWR((KK)*((CC)/4),3,pf3) PFWR((KK)*((CC)/4),4,pf4) PFWR((KK)*((CC)/4),5,pf5) }

__device__ __forceinline__ void ln32s(const float* __restrict__ in, int Si,
                                      float* __restrict__ out, int So,
                                      const float* __restrict__ g, const float* __restrict__ b,
                                      int t)
{
  if (t < 256){
    const int r = t >> 3, l8 = t & 7;
    const float* row = in + r*Si;
    float vals[12]; int cols[12];
    float s1 = 0.f, s2 = 0.f;
    #pragma unroll
    for (int i = 0; i < 12; ++i){
      int c = l8 + 8*i + 8*(r & 7); if (c >= 96) c -= 96;
      float a = row[c];
      cols[i] = c; vals[i] = a; s1 += a; s2 += a*a;
    }
    s1 += __shfl_xor(s1, 1); s2 += __shfl_xor(s2, 1);
    s1 += __shfl_xor(s1, 2); s2 += __shfl_xor(s2, 2);
    s1 += __shfl_xor(s1, 4); s2 += __shfl_xor(s2, 4);
    float mean = s1*(1.f/96.f);
    float var  = s2*(1.f/96.f) - mean*mean;
    float rsd = rsqrtf(var + 1e-5f);
    float* orow = out + r*So;
    #pragma unroll
    for (int i = 0; i < 12; ++i){
      int c = cols[i];
      orow[c] = (vals[i]-mean)*rsd*g[c] + b[c];
    }
  }
}

template<int K, int C, int LDW, bool GELU, bool HASB, bool RES, bool ACC>
__device__ __forceinline__ void mmR32(const float* __restrict__ inb, int S,
                                      const float* __restrict__ Wl, const float* __restrict__ bg,
                                      float* __restrict__ outb, int So,
                                      const float* __restrict__ residb, int Sr, int t)
{
  constexpr int C4 = C/4;
  const float4* __restrict__ W4 = (const float4*)Wl;
  for (int gi = t; gi < C4*16; gi += NTB){
    const int rp = gi & 15, c4 = gi >> 4;
    const float2* x0 = (const float2*)(inb + (2*rp)*S);
    const float2* x1 = (const float2*)(inb + (2*rp+1)*S);
    float4 a0 = HASB ? ((const float4*)bg)[c4] : make_float4(0.f,0.f,0.f,0.f);
    float4 a1 = a0;
    #pragma unroll 8
    for (int k2 = 0; k2 < K/2; ++k2){
      float2 xa = x0[k2], xb = x1[k2];
      float4 wA = W4[(2*k2)*(LDW/4) + c4];
      float4 wB = W4[(2*k2+1)*(LDW/4) + c4];
      fma4(a0, xa.x, wA); fma4(a0, xa.y, wB);
      fma4(a1, xb.x, wA); fma4(a1, xb.y, wB);
    }
    if (GELU){
      a0.x=gelu_f(a0.x); a0.y=gelu_f(a0.y); a0.z=gelu_f(a0.z); a0.w=gelu_f(a0.w);
      a1.x=gelu_f(a1.x); a1.y=gelu_f(a1.y); a1.z=gelu_f(a1.z); a1.w=gelu_f(a1.w);
    }
    if (RES){
      const float* r0 = residb + (2*rp)*Sr + 4*c4;
      const float* r1 = residb + (2*rp+1)*Sr + 4*c4;
      a0.x += r0[0]; a0.y += r0[1]; a0.z += r0[2]; a0.w += r0[3];
      a1.x += r1[0]; a1.y += r1[1]; a1.z += r1[2]; a1.w += r1[3];
    }
    float* o0 = outb + (2*rp)*So + 4*c4;
    float* o1 = outb + (2*rp+1)*So + 4*c4;
    if (ACC){
      a0.x += o0[0]; a0.y += o0[1]; a0.z += o0[2]; a0.w += o0[3];
      a1.x += o1[0]; a1.y += o1[1]; a1.z += o1[2]; a1.w += o1[3];
    }
    o0[0]=a0.x; o0[1]=a0.y; o0[2]=a0.z; o0[3]=a0.w;
    o1[0]=a1.x; o1[1]=a1.y; o1[2]=a1.z; o1[3]=a1.w;
  }
}

// ===================== Kernel B1 (round-14, unchanged) =====================
#define NBB1 (NPIX/4)
constexpr int BXIN  = 0;
constexpr int BXCUR = 3264;
constexpr int BXLN  = 6528;
constexpr int BHID  = 9792;
constexpr int BVB   = 14080;
constexpr int BMEAN = 15296;
constexpr int BVAR  = 15424;
constexpr int BWGT  = 15552;
constexpr int BWBUF = 15584;
constexpr int B1TOT = 27872;

__global__ __launch_bounds__(NTB)
void mva_phaseB1(const float* __restrict__ rgb, const float* __restrict__ fm,
                 const float* __restrict__ proj_err, float* __restrict__ ws,
                 const float* __restrict__ tv1_ln_g, const float* __restrict__ tv1_ln_b,
                 const float* __restrict__ tv1_w,
                 const float* __restrict__ to1_w, const float* __restrict__ to1_b,
                 const float* __restrict__ n1_ln_g, const float* __restrict__ n1_ln_b,
                 const float* __restrict__ n1_w1, const float* __restrict__ n1_b1,
                 const float* __restrict__ n1_w2, const float* __restrict__ n1_b2,
                 const float* __restrict__ tv2_ln_g, const float* __restrict__ tv2_ln_b,
                 const float* __restrict__ tv2_w)
{
  __shared__ __align__(16) float smem[B1TOT];
  const int t = threadIdx.x;
  const int bpx0 = blockIdx.x*4;
  float* WB = smem + BWBUF;
  float4* WB4 = (float4*)WB;
  float4 pf0 = make_float4(0,0,0,0), pf1 = pf0, pf2 = pf0, pf3 = pf0, pf4 = pf0, pf5 = pf0;

  for (int u = t; u < 2048; u += NTB){
    const int r = u >> 6, k = u & 63;
    const int pl = r >> 3, v = r & 7;
    float val = (k < 3) ? rgb[((bpx0+pl)*8 + v)*3 + k]
                        : fm[(bpx0+pl)*61 + (k-3)];
    smem[BXIN + r*102 + k] = val;
  }
  for (int u = t; u < 1024; u += NTB){
    const int r = u >> 5, c = u & 31;
    smem[BXIN + r*102 + 64 + c] = ws[(size_t)blockIdx.x*1024 + u];
  }
  if (t < 32){
    float pe = proj_err[(bpx0 + (t>>3))*8 + (t&7)];
    float wraw = fmaxf(-log10f(fabsf(pe) + 1e-6f), 0.f);
    float s = wraw;
    s += __shfl_xor(s, 1); s += __shfl_xor(s, 2); s += __shfl_xor(s, 4);
    smem[BWGT + t] = wraw / (s + 1e-6f);
  }
  stageW<96,32,32>(tv1_w, 0, WB, t);
  __syncthreads();

  ln32s(smem+BXIN, 102, smem+BXLN, 102, tv1_ln_g, tv1_ln_b, t);
  PFLOADG(to1_w, 96,96,96, 0)
  __syncthreads();
  mmR32<96,32,32,false,false,false,false>(smem+BXLN, 102, WB, nullptr, smem+BVB, 38, nullptr, 0, t);
  __syncthreads();
  if (t < 128){
    const int pl = t >> 5, c = t & 31;
    const float* wn = smem + BWGT + pl*8;
    float m = 0.f;
    #pragma unroll
    for (int v = 0; v < 8; ++v) m += wn[v]*smem[BVB + (pl*8+v)*38 + c];
    float vv = 0.f;
    #pragma unroll
    for (int v = 0; v < 8; ++v){ float d = smem[BVB + (pl*8+v)*38 + c] - m; vv += wn[v]*d*d; }
    smem[BMEAN + pl*32 + c] = m;
    smem[BVAR  + pl*32 + c] = vv;
  }
  PFWRITE(96,96)
  __syncthreads();
  for (int u = t; u < 3072; u += NTB){
    const int r = u & 31, c = u >> 5;
    const int pl = r >> 3;
    float val = (c < 32) ? smem[BVB + r*38 + c]
              : (c < 64) ? smem[BMEAN + pl*32 + (c-32)]
                         : smem[BVAR + pl*32 + (c-64)];
    smem[BXLN + r*102 + c] = val;
  }
  __syncthreads();
  PFLOADG(n1_w1, 96,128,256, 0)
  mmR32<96,96,96,false,true,true,false>(smem+BXLN, 102, WB, to1_b, smem+BXCUR, 102, smem+BXIN, 102, t);
  __syncthreads();
  ln32s(smem+BXCUR, 102, smem+BXLN, 102, n1_ln_g, n1_ln_b, t);
  PFWRITE(96,128)
  __syncthreads();
  PFLOADG(n1_w2, 128,96,96, 0)
  mmR32<96,128,128,true,true,false,false>(smem+BXLN, 102, WB, n1_b1, smem+BHID, 134, nullptr, 0, t);
  __syncthreads();
  PFWRITE(128,96)
  __syncthreads();
  PFLOADG(n1_w1, 96,128,256, 32)
  mmR32<128,96,96,false,false,false,false>(smem+BHID, 134, WB, nullptr, smem+BXCUR, 102, nullptr, 0, t);
  __syncthreads();
  PFWRITE(96,128)
  __syncthreads();
  PFLOADG(n1_w2 + 128*96, 128,96,96, 0)
  mmR32<96,128,128,true,true,false,false>(smem+BXLN, 102, WB, n1_b1 + 128, smem+BHID, 134, nullptr, 0, t);
  __syncthreads();
  PFWRITE(128,96)
  __syncthreads();
  PFLOADG(tv2_w, 96,32,32, 0)
  mmR32<128,96,96,false,true,true,true>(smem+BHID, 134, WB, n1_b2, smem+BXCUR, 102, smem+BXIN, 102, t);
  __syncthreads();
  ln32s(smem+BXCUR, 102, smem+BXLN, 102, tv2_ln_g, tv2_ln_b, t);
  PFWRITE(96,32)
  __syncthreads();
  mmR32<96,32,32,false,false,false,false>(smem+BXLN, 102, WB, nullptr, smem+BVB, 38, nullptr, 0, t);
  __syncthreads();
  if (t < 128){
    const int pl = t >> 5, c = t & 31;
    const float* wn = smem + BWGT + pl*8;
    float m = 0.f;
    #pragma unroll
    for (int v = 0; v < 8; ++v) m += wn[v]*smem[BVB + (pl*8+v)*38 + c];
    float vv = 0.f;
    #pragma unroll
    for (int v = 0; v < 8; ++v){ float d = smem[BVB + (pl*8+v)*38 + c] - m; vv += wn[v]*d*d; }
    smem[BMEAN + pl*32 + c] = m;
    smem[BVAR  + pl*32 + c] = vv;
  }
  __syncthreads();
  if (t < 384){
    const int pl = t / 96, c = t - pl*96;
    float val = (c < 32) ? smem[BVB + (pl*8)*38 + c]
              : (c < 64) ? smem[BMEAN + pl*32 + (c-32)]
                         : smem[BVAR + pl*32 + (c-64)];
    ws[(size_t)blockIdx.x*1024 + pl*256 + 96 + c] = val;
  }
}

// ===================== Kernel B2 (round-14, unchanged) =====================
#define NBB2 (NPIX/32)
constexpr int CXLN  = 0;
constexpr int CXIN  = 3264;
constexpr int CXS   = 6528;
constexpr int CTMP  = 9792;
constexpr int CHID  = 13056;
constexpr int CWBUF = 17344;
constexpr int B2TOT = 29632;

__global__ __launch_bounds__(NTB)
void mva_phaseB2(const float* __restrict__ rgb, const float* __restrict__ fm,
                 const float* __restrict__ ws,
                 const float* __restrict__ to2_w, const float* __restrict__ to2_b,
                 const float* __restrict__ n2_ln_g, const float* __restrict__ n2_ln_b,
                 const float* __restrict__ n2_w1, const float* __restrict__ n2_b1,
                 const float* __restrict__ n2_w2, const float* __restrict__ n2_b2,
                 const float* __restrict__ brdf_ln_g, const float* __restrict__ brdf_ln_b,
                 const float* __restrict__ brdf_w1, const float* __restrict__ brdf_b1,
                 const float* __restrict__ brdf_w2, const float* __restrict__ brdf_b2,
                 float* __restrict__ out)
{
  __shared__ __align__(16) float smem[B2TOT];
  const int t = threadIdx.x;
  const int bpx0 = blockIdx.x*32;
  float* WB = smem + CWBUF;
  float4* WB4 = (float4*)WB;
  float4 pf0 = make_float4(0,0,0,0), pf1 = pf0, pf2 = pf0, pf3 = pf0, pf4 = pf0, pf5 = pf0;

  for (int u = t; u < 3072; u += NTB){
    const int r = u / 96, c = u - r*96;
    const int px = bpx0 + r;
    const size_t ab = (size_t)px*256;
    smem[CXLN + r*102 + c] = ws[ab + 96 + c];
    float xv = (c < 3)  ? rgb[((size_t)px*8)*3 + c]
             : (c < 64) ? fm[(size_t)px*61 + (c-3)]
                        : ws[ab + (c-64)];
    smem[CXIN + r*102 + c] = xv;
  }
  stageW<96,96,96>(to2_w, 0, WB, t);
  __syncthreads();

  PFLOADG(n2_w1, 96,128,256, 0)
  mmR32<96,96,96,false,true,true,false>(smem+CXLN, 102, WB, to2_b, smem+CXS, 102, smem+CXIN, 102, t);
  __syncthreads();
  ln32s(smem+CXS, 102, smem+CXLN, 102, n2_ln_g, n2_ln_b, t);
  PFWRITE(96,128)
  __syncthreads();
  PFLOADG(n2_w2, 128,96,96, 0)
  mmR32<96,128,128,true,true,false,false>(smem+CXLN, 102, WB, n2_b1, smem+CHID, 134, nullptr, 0, t);
  __syncthreads();
  PFWRITE(128,96)
  __syncthreads();
  PFLOADG(n2_w1, 96,128,256, 32)
  mmR32<128,96,96,false,false,false,false>(smem+CHID, 134, WB, nullptr, smem+CTMP, 102, nullptr, 0, t);
  __syncthreads();
  PFWRITE(96,128)
  __syncthreads();
  PFLOADG(n2_w2 + 128*96, 128,96,96, 0)
  mmR32<96,128,128,true,true,false,false>(smem+CXLN, 102, WB, n2_b1 + 128, smem+CHID, 134, nullptr, 0, t);
  __syncthreads();
  PFWRITE(128,96)
  __syncthreads();
  PFLOADG(brdf_w1, 96,128,128, 0)
  mmR32<128,96,96,false,true,true,true>(smem+CHID, 134, WB, n2_b2, smem+CTMP, 102, smem+CXIN, 102, t);
  __syncthreads();
  ln32s(smem+CTMP, 102, smem+CXLN, 102, brdf_ln_g, brdf_ln_b, t);
  PFWRITE(96,128)
  __syncthreads();
  PFLOADG(brdf_w2, 128,64,128, 0)
  mmR32<96,128,128,true,true,false,false>(smem+CXLN, 102, WB, brdf_b1, smem+CHID, 134, nullptr, 0, t);
  __syncthreads();
  PFWRITE(128,64)
  __syncthreads();
  float* outp = out + (size_t)bpx0*128;
  PFLOADG(brdf_w2, 128,64,128, 16)
  mmR32<128,64,64,false,true,false,false>(smem+CHID, 134, WB, brdf_b2, outp, 128, nullptr, 0, t);
  __syncthreads();
  PFWRITE(128,64)
  __syncthreads();
  mmR32<128,64,64,false,true,false,false>(smem+CHID, 134, WB, brdf_b2 + 64, outp + 64, 128, nullptr, 0, t);
}

extern "C" void kernel_launch(void* const* d_in, const int* in_sizes, int n_in,
                              void* d_out, int out_size, void* d_ws, size_t ws_size,
                              hipStream_t stream)
{
  (void)in_sizes; (void)n_in; (void)ws_size; (void)out_size;
  int i = 0;
  const float* rgb      = (const float*)d_in[i++];
  const float* fm       = (const float*)d_in[i++];
  const float* view_dir = (const float*)d_in[i++];
  const float* proj_err = (const float*)d_in[i++];
  const float* normal   = (const float*)d_in[i++];
  const float* DL       = (const float*)d_in[i++];
  const float* pbr_ln_g = (const float*)d_in[i++];
  const float* pbr_ln_b = (const float*)d_in[i++];
  const float* pbr_w1   = (const float*)d_in[i++];
  const float* pbr_b1   = (const float*)d_in[i++];
  const float* pbr_w2   = (const float*)d_in[i++];
  const float* pbr_b2   = (const float*)d_in[i++];
  const float* pbr_w3   = (const float*)d_in[i++];
  const float* pbr_b3   = (const float*)d_in[i++];
  const float* pbr_w4   = (const float*)d_in[i++];
  const float* pbr_b4   = (const float*)d_in[i++];
  const float* tv1_ln_g = (const float*)d_in[i++];
  const float* tv1_ln_b = (const float*)d_in[i++];
  const float* tv1_w    = (const float*)d_in[i++];
  const float* to1_w    = (const float*)d_in[i++];
  const float* to1_b    = (const float*)d_in[i++];
  const float* n1_ln_g  = (const float*)d_in[i++];
  const float* n1_ln_b  = (const float*)d_in[i++];
  const float* n1_w1    = (const float*)d_in[i++];
  const float* n1_b1    = (const float*)d_in[i++];
  const float* n1_w2    = (const float*)d_in[i++];
  const float* n1_b2    = (const float*)d_in[i++];
  const float* tv2_ln_g = (const float*)d_in[i++];
  const float* tv2_ln_b = (const float*)d_in[i++];
  const float* tv2_w    = (const float*)d_in[i++];
  const float* to2_w    = (const float*)d_in[i++];
  const float* to2_b    = (const float*)d_in[i++];
  const float* n2_ln_g  = (const float*)d_in[i++];
  const float* n2_ln_b  = (const float*)d_in[i++];
  const float* n2_w1    = (const float*)d_in[i++];
  const float* n2_b1    = (const float*)d_in[i++];
  const float* n2_w2    = (const float*)d_in[i++];
  const float* n2_b2    = (const float*)d_in[i++];
  const float* brdf_ln_g= (const float*)d_in[i++];
  const float* brdf_ln_b= (const float*)d_in[i++];
  const float* brdf_w1  = (const float*)d_in[i++];
  const float* brdf_b1  = (const float*)d_in[i++];
  const float* brdf_w2  = (const float*)d_in[i++];
  const float* brdf_b2  = (const float*)d_in[i++];

  float* ws = (float*)d_ws;

  mva_phaseA<<<dim3(NBA), dim3(NTA), 0, stream>>>(
      view_dir, normal, DL, pbr_ln_g, pbr_ln_b,
      pbr_w1, pbr_b1, pbr_w2, pbr_b2, pbr_w3, pbr_b3, pbr_w4, pbr_b4, ws);

  mva_phaseB1<<<dim3(NBB1), dim3(NTB), 0, stream>>>(
      rgb, fm, proj_err, ws,
      tv1_ln_g, tv1_ln_b, tv1_w, to1_w, to1_b,
      n1_ln_g, n1_ln_b, n1_w1, n1_b1, n1_w2, n1_b2,
      tv2_ln_g, tv2_ln_b, tv2_w);

  mva_phaseB2<<<dim3(NBB2), dim3(NTB), 0, stream>>>(
      rgb, fm, ws,
      to2_w, to2_b,
      n2_ln_g, n2_ln_b, n2_w1, n2_b1, n2_w2, n2_b2,
      brdf_ln_g, brdf_ln_b, brdf_w1, brdf_b1, brdf_w2, brdf_b2,
      (float*)d_out);
}

// Round 18
// 1087.592 us; speedup vs baseline: 1.2288x; 1.2288x over previous
//
#include <hip/hip_runtime.h>
#include <math.h>

// MultiViewAggregation — final (round-14 configuration, best measured 1086 us).
// A: 2px row-batched MLP (768 thr), LDS ping-pong activations, T14 weight
//    prefetch (global->reg early, ds_write after barrier).
// B1/B2: T14 prefetch on all weight stages.

#define NPIX 16384

__device__ __forceinline__ float elu_f(float x){ return x > 0.f ? x : (__expf(x) - 1.f); }
__device__ __forceinline__ float gelu_f(float x){ return 0.5f*x*(1.f + erff(x*0.70710678118654752f)); }

__device__ __forceinline__ void fma4(float4& a, float s, const float4 w){
  a.x = fmaf(s, w.x, a.x); a.y = fmaf(s, w.y, a.y);
  a.z = fmaf(s, w.z, a.z); a.w = fmaf(s, w.w, a.w);
}
__device__ __forceinline__ float4 elu4f(float4 a){
  return make_float4(elu_f(a.x), elu_f(a.y), elu_f(a.z), elu_f(a.w));
}

// ===================== Kernel A =====================
#define NTA 768
#define NBA (NPIX/2)

constexpr int AYA   = 0;
constexpr int AYB   = 13056;
constexpr int AWB   = 26112;
constexpr int AXL   = 30208;
constexpr int ABIAS = 31744;
constexpr int ATOT  = 31968;

template<int K, int SI, bool DOELU>
__device__ __forceinline__ void mmA64(const float* __restrict__ Xin,
                                      const float* __restrict__ WB,
                                      const float* __restrict__ bias,
                                      float* __restrict__ Yout, int t)
{
  const int rq = t >> 4, c4 = t & 15;
  const float* x0 = Xin + (4*rq+0)*SI;
  const float* x1 = Xin + (4*rq+1)*SI;
  const float* x2 = Xin + (4*rq+2)*SI;
  const float* x3 = Xin + (4*rq+3)*SI;
  const float4* __restrict__ W4 = (const float4*)WB;
  const float4 b = ((const float4*)bias)[c4];
  float4 a0=b, a1=b, a2=b, a3=b;
  #pragma unroll
  for (int k2 = 0; k2 < K/2; ++k2){
    const float2 xa = *(const float2*)(x0 + 2*k2);
    const float2 xb = *(const float2*)(x1 + 2*k2);
    const float2 xc = *(const float2*)(x2 + 2*k2);
    const float2 xd = *(const float2*)(x3 + 2*k2);
    const float4 wA = W4[(2*k2)*16 + c4];
    const float4 wB = W4[(2*k2+1)*16 + c4];
    fma4(a0, xa.x, wA); fma4(a0, xa.y, wB);
    fma4(a1, xb.x, wA); fma4(a1, xb.y, wB);
    fma4(a2, xc.x, wA); fma4(a2, xc.y, wB);
    fma4(a3, xd.x, wA); fma4(a3, xd.y, wB);
  }
  if (DOELU){ a0 = elu4f(a0); a1 = elu4f(a1); a2 = elu4f(a2); a3 = elu4f(a3); }
  *(float4*)(Yout + (4*rq+0)*68 + 4*c4) = a0;
  *(float4*)(Yout + (4*rq+1)*68 + 4*c4) = a1;
  *(float4*)(Yout + (4*rq+2)*68 + 4*c4) = a2;
  *(float4*)(Yout + (4*rq+3)*68 + 4*c4) = a3;
}

__device__ __forceinline__ void mmA32(const float* __restrict__ Xin,
                                      const float* __restrict__ WB,
                                      const float* __restrict__ bias,
                                      float* __restrict__ F, int t)
{
  const int rq = t >> 4, c2 = t & 15;
  const float* x0 = Xin + (4*rq+0)*68;
  const float* x1 = Xin + (4*rq+1)*68;
  const float* x2 = Xin + (4*rq+2)*68;
  const float* x3 = Xin + (4*rq+3)*68;
  const float2* __restrict__ W2 = (const float2*)WB;
  const float2 b = ((const float2*)bias)[c2];
  float2 a0=b, a1=b, a2=b, a3=b;
  #pragma unroll
  for (int k2 = 0; k2 < 32; ++k2){
    const float2 xa = *(const float2*)(x0 + 2*k2);
    const float2 xb = *(const float2*)(x1 + 2*k2);
    const float2 xc = *(const float2*)(x2 + 2*k2);
    const float2 xd = *(const float2*)(x3 + 2*k2);
    const float2 wA = W2[(2*k2)*16 + c2];
    const float2 wB = W2[(2*k2+1)*16 + c2];
    a0.x = fmaf(xa.x, wA.x, a0.x); a0.y = fmaf(xa.x, wA.y, a0.y);
    a0.x = fmaf(xa.y, wB.x, a0.x); a0.y = fmaf(xa.y, wB.y, a0.y);
    a1.x = fmaf(xb.x, wA.x, a1.x); a1.y = fmaf(xb.x, wA.y, a1.y);
    a1.x = fmaf(xb.y, wB.x, a1.x); a1.y = fmaf(xb.y, wB.y, a1.y);
    a2.x = fmaf(xc.x, wA.x, a2.x); a2.y = fmaf(xc.x, wA.y, a2.y);
    a2.x = fmaf(xc.y, wB.x, a2.x); a2.y = fmaf(xc.y, wB.y, a2.y);
    a3.x = fmaf(xd.x, wA.x, a3.x); a3.y = fmaf(xd.x, wA.y, a3.y);
    a3.x = fmaf(xd.y, wB.x, a3.x); a3.y = fmaf(xd.y, wB.y, a3.y);
  }
  *(float2*)(F + (4*rq+0)*34 + 2*c2) = a0;
  *(float2*)(F + (4*rq+1)*34 + 2*c2) = a1;
  *(float2*)(F + (4*rq+2)*34 + 2*c2) = a2;
  *(float2*)(F + (4*rq+3)*34 + 2*c2) = a3;
}

__global__ __launch_bounds__(NTA)
void mva_phaseA(const float* __restrict__ view_dir, const float* __restrict__ normal,
                const float* __restrict__ DL,
                const float* __restrict__ ln_g, const float* __restrict__ ln_b,
                const float* __restrict__ w1, const float* __restrict__ b1,
                const float* __restrict__ w2, const float* __restrict__ b2,
                const float* __restrict__ w3, const float* __restrict__ b3,
                const float* __restrict__ w4, const float* __restrict__ b4,
                float* __restrict__ feat)
{
  __shared__ __align__(16) float smem[ATOT];
  const int t = threadIdx.x;
  const int bpx0 = blockIdx.x*2;
  float4* WB4 = (float4*)(smem + AWB);

  {
    const float4* s = (const float4*)w1;
    for (int i = t; i < 128; i += NTA){
      const int k = i >> 4, c4 = i & 15;
      WB4[i] = (k < 7) ? s[k*16 + c4] : make_float4(0.f,0.f,0.f,0.f);
    }
    float4* d = (float4*)(smem+ABIAS);
    if (t >= 256 && t < 272)      d[t-256]      = ((const float4*)b1)[t-256];
    else if (t >= 272 && t < 288) d[16 + t-272] = ((const float4*)b2)[t-272];
    else if (t >= 288 && t < 304) d[32 + t-288] = ((const float4*)b3)[t-288];
    else if (t >= 304 && t < 312) d[48 + t-304] = ((const float4*)b4)[t-304];
  }
  if (t < 192){
    const int pl = t / 96, rr = t - pl*96;
    const int sg = rr >> 3, view = rr & 7;
    const int px = bpx0 + pl;
    const float nm0 = normal[px*3+0], nm1 = normal[px*3+1], nm2 = normal[px*3+2];
    const float* vd = view_dir + (px*8 + view)*3;
    const float vd0 = vd[0], vd1 = vd[1], vd2 = vd[2];
    const float* dl = DL + px*84 + sg*7;
    const float d0=dl[0], d1=dl[1], d2=dl[2], d3=dl[3], d4=dl[4], d5=dl[5], d6=dl[6];

    const float DLdotN = d0*nm0 + d1*nm1 + d2*nm2;
    const float hv     = (d0*vd0 + d1*vd1 + d2*vd2 + 1.f)*0.5f;
    const float fres   = exp2f((-5.55472f*hv - 6.98316f)*hv);
    const float VdotN  = vd0*nm0 + vd1*nm1 + vd2*nm2;

    const float x0 = DLdotN, x1 = d3, x2 = d4, x3 = d5, x4 = d6, x5 = fres, x6 = VdotN;
    const float m  = (x0+x1+x2+x3+x4+x5+x6)*(1.f/7.f);
    float q, var = 0.f;
    q = x0-m; var += q*q; q = x1-m; var += q*q; q = x2-m; var += q*q;
    q = x3-m; var += q*q; q = x4-m; var += q*q; q = x5-m; var += q*q;
    q = x6-m; var += q*q;
    const float rs = rsqrtf(var*(1.f/7.f) + 1e-5f);
    float* xl = smem + AXL + t*8;
    xl[0] = (x0-m)*rs*ln_g[0] + ln_b[0];
    xl[1] = (x1-m)*rs*ln_g[1] + ln_b[1];
    xl[2] = (x2-m)*rs*ln_g[2] + ln_b[2];
    xl[3] = (x3-m)*rs*ln_g[3] + ln_b[3];
    xl[4] = (x4-m)*rs*ln_g[4] + ln_b[4];
    xl[5] = (x5-m)*rs*ln_g[5] + ln_b[5];
    xl[6] = (x6-m)*rs*ln_g[6] + ln_b[6];
    xl[7] = 0.f;
  }
  __syncthreads();

  float4 p0 = ((const float4*)w2)[t];
  float4 p1 = (t < 256) ? ((const float4*)w2)[t + 768] : make_float4(0.f,0.f,0.f,0.f);
  mmA64<8,8,true>(smem+AXL, smem+AWB, smem+ABIAS+0, smem+AYA, t);
  __syncthreads();
  WB4[t] = p0; if (t < 256) WB4[t + 768] = p1;
  __syncthreads();

  p0 = ((const float4*)w3)[t];
  p1 = (t < 256) ? ((const float4*)w3)[t + 768] : make_float4(0.f,0.f,0.f,0.f);
  mmA64<64,68,true>(smem+AYA, smem+AWB, smem+ABIAS+64, smem+AYB, t);
  __syncthreads();
  WB4[t] = p0; if (t < 256) WB4[t + 768] = p1;
  __syncthreads();

  p0 = (t < 512) ? ((const float4*)w4)[t] : make_float4(0.f,0.f,0.f,0.f);
  mmA64<64,68,true>(smem+AYB, smem+AWB, smem+ABIAS+128, smem+AYA, t);
  __syncthreads();
  if (t < 512) WB4[t] = p0;
  __syncthreads();

  mmA32(smem+AYA, smem+AWB, smem+ABIAS+192, smem+AYB, t);
  __syncthreads();

  if (t < 512){
    const int pl = t >> 8, idx = t & 255;
    const int v = idx >> 5, c = idx & 31;
    float s = 0.f;
    #pragma unroll
    for (int sg = 0; sg < 12; ++sg) s += smem[AYB + (pl*96 + sg*8 + v)*34 + c];
    feat[(size_t)(bpx0 + pl)*256 + idx] = s;
  }
}

// ===================== Shared B machinery =====================
#define NTB 512

template<int KK, int CC, int LDWG>
__device__ __forceinline__ void stageW(const float* __restrict__ Wg, int c4off,
                                       float* __restrict__ wbuf, int t)
{
  constexpr int C4 = CC/4;
  constexpr int N4 = KK*C4;
  const float4* __restrict__ s = (const float4*)Wg;
  float4* d = (float4*)wbuf;
  for (int i = t; i < N4; i += NTB){
    const int k = i / C4, c4 = i - k*C4;
    d[i] = s[k*(LDWG/4) + c4off + c4];
  }
}

#define PFSLOT(Wg, KK, CC, LDWG, C4OFF, SLOT, PFV) { \
  const int _i = t + (SLOT)*512; \
  if ((KK)*((CC)/4) > (SLOT)*512 && _i < (KK)*((CC)/4)){ \
    const int _k = _i/((CC)/4), _c = _i - _k*((CC)/4); \
    PFV = ((const float4*)(Wg))[_k*((LDWG)/4) + (C4OFF) + _c]; } }

#define PFLOADG(Wg, KK, CC, LDWG, C4OFF) \
  PFSLOT(Wg,KK,CC,LDWG,C4OFF,0,pf0) PFSLOT(Wg,KK,CC,LDWG,C4OFF,1,pf1) \
  PFSLOT(Wg,KK,CC,LDWG,C4OFF,2,pf2) PFSLOT(Wg,KK,CC,LDWG,C4OFF,3,pf3) \
  PFSLOT(Wg,KK,CC,LDWG,C4OFF,4,pf4) PFSLOT(Wg,KK,CC,LDWG,C4OFF,5,pf5)

#define PFWR(N4, SLOT, PFV) { if ((N4) > (SLOT)*512 && t + (SLOT)*512 < (N4)) WB4[t+(SLOT)*512] = PFV; }
#define PFWRITE(KK, CC) { \
  PFWR((KK)*((CC)/4),0,pf0) PFWR((KK)*((CC)/4),1,pf1) PFWR((KK)*((CC)/4),2,pf2) \
  PFWR((KK)*((CC)/4),3,pf3) PFWR((KK)*((CC)/4),4,pf4) PFWR((KK)*((CC)/4),5,pf5) }

__device__ __forceinline__ void ln32s(const float* __restrict__ in, int Si,
                                      float* __restrict__ out, int So,
                                      const float* __restrict__ g, const float* __restrict__ b,
                                      int t)
{
  if (t < 256){
    const int r = t >> 3, l8 = t & 7;
    const float* row = in + r*Si;
    float vals[12]; int cols[12];
    float s1 = 0.f, s2 = 0.f;
    #pragma unroll
    for (int i = 0; i < 12; ++i){
      int c = l8 + 8*i + 8*(r & 7); if (c >= 96) c -= 96;
      float a = row[c];
      cols[i] = c; vals[i] = a; s1 += a; s2 += a*a;
    }
    s1 += __shfl_xor(s1, 1); s2 += __shfl_xor(s2, 1);
    s1 += __shfl_xor(s1, 2); s2 += __shfl_xor(s2, 2);
    s1 += __shfl_xor(s1, 4); s2 += __shfl_xor(s2, 4);
    float mean = s1*(1.f/96.f);
    float var  = s2*(1.f/96.f) - mean*mean;
    float rsd = rsqrtf(var + 1e-5f);
    float* orow = out + r*So;
    #pragma unroll
    for (int i = 0; i < 12; ++i){
      int c = cols[i];
      orow[c] = (vals[i]-mean)*rsd*g[c] + b[c];
    }
  }
}

template<int K, int C, int LDW, bool GELU, bool HASB, bool RES, bool ACC>
__device__ __forceinline__ void mmR32(const float* __restrict__ inb, int S,
                                      const float* __restrict__ Wl, const float* __restrict__ bg,
                                      float* __restrict__ outb, int So,
                                      const float* __restrict__ residb, int Sr, int t)
{
  constexpr int C4 = C/4;
  const float4* __restrict__ W4 = (const float4*)Wl;
  for (int gi = t; gi < C4*16; gi += NTB){
    const int rp = gi & 15, c4 = gi >> 4;
    const float2* x0 = (const float2*)(inb + (2*rp)*S);
    const float2* x1 = (const float2*)(inb + (2*rp+1)*S);
    float4 a0 = HASB ? ((const float4*)bg)[c4] : make_float4(0.f,0.f,0.f,0.f);
    float4 a1 = a0;
    #pragma unroll 8
    for (int k2 = 0; k2 < K/2; ++k2){
      float2 xa = x0[k2], xb = x1[k2];
      float4 wA = W4[(2*k2)*(LDW/4) + c4];
      float4 wB = W4[(2*k2+1)*(LDW/4) + c4];
      fma4(a0, xa.x, wA); fma4(a0, xa.y, wB);
      fma4(a1, xb.x, wA); fma4(a1, xb.y, wB);
    }
    if (GELU){
      a0.x=gelu_f(a0.x); a0.y=gelu_f(a0.y); a0.z=gelu_f(a0.z); a0.w=gelu_f(a0.w);
      a1.x=gelu_f(a1.x); a1.y=gelu_f(a1.y); a1.z=gelu_f(a1.z); a1.w=gelu_f(a1.w);
    }
    if (RES){
      const float* r0 = residb + (2*rp)*Sr + 4*c4;
      const float* r1 = residb + (2*rp+1)*Sr + 4*c4;
      a0.x += r0[0]; a0.y += r0[1]; a0.z += r0[2]; a0.w += r0[3];
      a1.x += r1[0]; a1.y += r1[1]; a1.z += r1[2]; a1.w += r1[3];
    }
    float* o0 = outb + (2*rp)*So + 4*c4;
    float* o1 = outb + (2*rp+1)*So + 4*c4;
    if (ACC){
      a0.x += o0[0]; a0.y += o0[1]; a0.z += o0[2]; a0.w += o0[3];
      a1.x += o1[0]; a1.y += o1[1]; a1.z += o1[2]; a1.w += o1[3];
    }
    o0[0]=a0.x; o0[1]=a0.y; o0[2]=a0.z; o0[3]=a0.w;
    o1[0]=a1.x; o1[1]=a1.y; o1[2]=a1.z; o1[3]=a1.w;
  }
}

// ===================== Kernel B1 (T14 prefetch) =====================
#define NBB1 (NPIX/4)
constexpr int BXIN  = 0;
constexpr int BXCUR = 3264;
constexpr int BXLN  = 6528;
constexpr int BHID  = 9792;
constexpr int BVB   = 14080;
constexpr int BMEAN = 15296;
constexpr int BVAR  = 15424;
constexpr int BWGT  = 15552;
constexpr int BWBUF = 15584;
constexpr int B1TOT = 27872;

__global__ __launch_bounds__(NTB)
void mva_phaseB1(const float* __restrict__ rgb, const float* __restrict__ fm,
                 const float* __restrict__ proj_err, float* __restrict__ ws,
                 const float* __restrict__ tv1_ln_g, const float* __restrict__ tv1_ln_b,
                 const float* __restrict__ tv1_w,
                 const float* __restrict__ to1_w, const float* __restrict__ to1_b,
                 const float* __restrict__ n1_ln_g, const float* __restrict__ n1_ln_b,
                 const float* __restrict__ n1_w1, const float* __restrict__ n1_b1,
                 const float* __restrict__ n1_w2, const float* __restrict__ n1_b2,
                 const float* __restrict__ tv2_ln_g, const float* __restrict__ tv2_ln_b,
                 const float* __restrict__ tv2_w)
{
  __shared__ __align__(16) float smem[B1TOT];
  const int t = threadIdx.x;
  const int bpx0 = blockIdx.x*4;
  float* WB = smem + BWBUF;
  float4* WB4 = (float4*)WB;
  float4 pf0 = make_float4(0,0,0,0), pf1 = pf0, pf2 = pf0, pf3 = pf0, pf4 = pf0, pf5 = pf0;

  for (int u = t; u < 2048; u += NTB){
    const int r = u >> 6, k = u & 63;
    const int pl = r >> 3, v = r & 7;
    float val = (k < 3) ? rgb[((bpx0+pl)*8 + v)*3 + k]
                        : fm[(bpx0+pl)*61 + (k-3)];
    smem[BXIN + r*102 + k] = val;
  }
  for (int u = t; u < 1024; u += NTB){
    const int r = u >> 5, c = u & 31;
    smem[BXIN + r*102 + 64 + c] = ws[(size_t)blockIdx.x*1024 + u];
  }
  if (t < 32){
    float pe = proj_err[(bpx0 + (t>>3))*8 + (t&7)];
    float wraw = fmaxf(-log10f(fabsf(pe) + 1e-6f), 0.f);
    float s = wraw;
    s += __shfl_xor(s, 1); s += __shfl_xor(s, 2); s += __shfl_xor(s, 4);
    smem[BWGT + t] = wraw / (s + 1e-6f);
  }
  stageW<96,32,32>(tv1_w, 0, WB, t);
  __syncthreads();

  ln32s(smem+BXIN, 102, smem+BXLN, 102, tv1_ln_g, tv1_ln_b, t);
  PFLOADG(to1_w, 96,96,96, 0)
  __syncthreads();
  mmR32<96,32,32,false,false,false,false>(smem+BXLN, 102, WB, nullptr, smem+BVB, 38, nullptr, 0, t);
  __syncthreads();
  if (t < 128){
    const int pl = t >> 5, c = t & 31;
    const float* wn = smem + BWGT + pl*8;
    float m = 0.f;
    #pragma unroll
    for (int v = 0; v < 8; ++v) m += wn[v]*smem[BVB + (pl*8+v)*38 + c];
    float vv = 0.f;
    #pragma unroll
    for (int v = 0; v < 8; ++v){ float d = smem[BVB + (pl*8+v)*38 + c] - m; vv += wn[v]*d*d; }
    smem[BMEAN + pl*32 + c] = m;
    smem[BVAR  + pl*32 + c] = vv;
  }
  PFWRITE(96,96)
  __syncthreads();
  for (int u = t; u < 3072; u += NTB){
    const int r = u & 31, c = u >> 5;
    const int pl = r >> 3;
    float val = (c < 32) ? smem[BVB + r*38 + c]
              : (c < 64) ? smem[BMEAN + pl*32 + (c-32)]
                         : smem[BVAR + pl*32 + (c-64)];
    smem[BXLN + r*102 + c] = val;
  }
  __syncthreads();
  PFLOADG(n1_w1, 96,128,256, 0)
  mmR32<96,96,96,false,true,true,false>(smem+BXLN, 102, WB, to1_b, smem+BXCUR, 102, smem+BXIN, 102, t);
  __syncthreads();
  ln32s(smem+BXCUR, 102, smem+BXLN, 102, n1_ln_g, n1_ln_b, t);
  PFWRITE(96,128)
  __syncthreads();
  PFLOADG(n1_w2, 128,96,96, 0)
  mmR32<96,128,128,true,true,false,false>(smem+BXLN, 102, WB, n1_b1, smem+BHID, 134, nullptr, 0, t);
  __syncthreads();
  PFWRITE(128,96)
  __syncthreads();
  PFLOADG(n1_w1, 96,128,256, 32)
  mmR32<128,96,96,false,false,false,false>(smem+BHID, 134, WB, nullptr, smem+BXCUR, 102, nullptr, 0, t);
  __syncthreads();
  PFWRITE(96,128)
  __syncthreads();
  PFLOADG(n1_w2 + 128*96, 128,96,96, 0)
  mmR32<96,128,128,true,true,false,false>(smem+BXLN, 102, WB, n1_b1 + 128, smem+BHID, 134, nullptr, 0, t);
  __syncthreads();
  PFWRITE(128,96)
  __syncthreads();
  PFLOADG(tv2_w, 96,32,32, 0)
  mmR32<128,96,96,false,true,true,true>(smem+BHID, 134, WB, n1_b2, smem+BXCUR, 102, smem+BXIN, 102, t);
  __syncthreads();
  ln32s(smem+BXCUR, 102, smem+BXLN, 102, tv2_ln_g, tv2_ln_b, t);
  PFWRITE(96,32)
  __syncthreads();
  mmR32<96,32,32,false,false,false,false>(smem+BXLN, 102, WB, nullptr, smem+BVB, 38, nullptr, 0, t);
  __syncthreads();
  if (t < 128){
    const int pl = t >> 5, c = t & 31;
    const float* wn = smem + BWGT + pl*8;
    float m = 0.f;
    #pragma unroll
    for (int v = 0; v < 8; ++v) m += wn[v]*smem[BVB + (pl*8+v)*38 + c];
    float vv = 0.f;
    #pragma unroll
    for (int v = 0; v < 8; ++v){ float d = smem[BVB + (pl*8+v)*38 + c] - m; vv += wn[v]*d*d; }
    smem[BMEAN + pl*32 + c] = m;
    smem[BVAR  + pl*32 + c] = vv;
  }
  __syncthreads();
  if (t < 384){
    const int pl = t / 96, c = t - pl*96;
    float val = (c < 32) ? smem[BVB + (pl*8)*38 + c]
              : (c < 64) ? smem[BMEAN + pl*32 + (c-32)]
                         : smem[BVAR + pl*32 + (c-64)];
    ws[(size_t)blockIdx.x*1024 + pl*256 + 96 + c] = val;
  }
}

// ===================== Kernel B2 (T14 prefetch) =====================
#define NBB2 (NPIX/32)
constexpr int CXLN  = 0;
constexpr int CXIN  = 3264;
constexpr int CXS   = 6528;
constexpr int CTMP  = 9792;
constexpr int CHID  = 13056;
constexpr int CWBUF = 17344;
constexpr int B2TOT = 29632;

__global__ __launch_bounds__(NTB)
void mva_phaseB2(const float* __restrict__ rgb, const float* __restrict__ fm,
                 const float* __restrict__ ws,
                 const float* __restrict__ to2_w, const float* __restrict__ to2_b,
                 const float* __restrict__ n2_ln_g, const float* __restrict__ n2_ln_b,
                 const float* __restrict__ n2_w1, const float* __restrict__ n2_b1,
                 const float* __restrict__ n2_w2, const float* __restrict__ n2_b2,
                 const float* __restrict__ brdf_ln_g, const float* __restrict__ brdf_ln_b,
                 const float* __restrict__ brdf_w1, const float* __restrict__ brdf_b1,
                 const float* __restrict__ brdf_w2, const float* __restrict__ brdf_b2,
                 float* __restrict__ out)
{
  __shared__ __align__(16) float smem[B2TOT];
  const int t = threadIdx.x;
  const int bpx0 = blockIdx.x*32;
  float* WB = smem + CWBUF;
  float4* WB4 = (float4*)WB;
  float4 pf0 = make_float4(0,0,0,0), pf1 = pf0, pf2 = pf0, pf3 = pf0, pf4 = pf0, pf5 = pf0;

  for (int u = t; u < 3072; u += NTB){
    const int r = u / 96, c = u - r*96;
    const int px = bpx0 + r;
    const size_t ab = (size_t)px*256;
    smem[CXLN + r*102 + c] = ws[ab + 96 + c];
    float xv = (c < 3)  ? rgb[((size_t)px*8)*3 + c]
             : (c < 64) ? fm[(size_t)px*61 + (c-3)]
                        : ws[ab + (c-64)];
    smem[CXIN + r*102 + c] = xv;
  }
  stageW<96,96,96>(to2_w, 0, WB, t);
  __syncthreads();

  PFLOADG(n2_w1, 96,128,256, 0)
  mmR32<96,96,96,false,true,true,false>(smem+CXLN, 102, WB, to2_b, smem+CXS, 102, smem+CXIN, 102, t);
  __syncthreads();
  ln32s(smem+CXS, 102, smem+CXLN, 102, n2_ln_g, n2_ln_b, t);
  PFWRITE(96,128)
  __syncthreads();
  PFLOADG(n2_w2, 128,96,96, 0)
  mmR32<96,128,128,true,true,false,false>(smem+CXLN, 102, WB, n2_b1, smem+CHID, 134, nullptr, 0, t);
  __syncthreads();
  PFWRITE(128,96)
  __syncthreads();
  PFLOADG(n2_w1, 96,128,256, 32)
  mmR32<128,96,96,false,false,false,false>(smem+CHID, 134, WB, nullptr, smem+CTMP, 102, nullptr, 0, t);
  __syncthreads();
  PFWRITE(96,128)
  __syncthreads();
  PFLOADG(n2_w2 + 128*96, 128,96,96, 0)
  mmR32<96,128,128,true,true,false,false>(smem+CXLN, 102, WB, n2_b1 + 128, smem+CHID, 134, nullptr, 0, t);
  __syncthreads();
  PFWRITE(128,96)
  __syncthreads();
  PFLOADG(brdf_w1, 96,128,128, 0)
  mmR32<128,96,96,false,true,true,true>(smem+CHID, 134, WB, n2_b2, smem+CTMP, 102, smem+CXIN, 102, t);
  __syncthreads();
  ln32s(smem+CTMP, 102, smem+CXLN, 102, brdf_ln_g, brdf_ln_b, t);
  PFWRITE(96,128)
  __syncthreads();
  PFLOADG(brdf_w2, 128,64,128, 0)
  mmR32<96,128,128,true,true,false,false>(smem+CXLN, 102, WB, brdf_b1, smem+CHID, 134, nullptr, 0, t);
  __syncthreads();
  PFWRITE(128,64)
  __syncthreads();
  float* outp = out + (size_t)bpx0*128;
  PFLOADG(brdf_w2, 128,64,128, 16)
  mmR32<128,64,64,false,true,false,false>(smem+CHID, 134, WB, brdf_b2, outp, 128, nullptr, 0, t);
  __syncthreads();
  PFWRITE(128,64)
  __syncthreads();
  mmR32<128,64,64,false,true,false,false>(smem+CHID, 134, WB, brdf_b2 + 64, outp + 64, 128, nullptr, 0, t);
}

extern "C" void kernel_launch(void* const* d_in, const int* in_sizes, int n_in,
                              void* d_out, int out_size, void* d_ws, size_t ws_size,
                              hipStream_t stream)
{
  (void)in_sizes; (void)n_in; (void)ws_size; (void)out_size;
  int i = 0;
  const float* rgb      = (const float*)d_in[i++];
  const float* fm       = (const float*)d_in[i++];
  const float* view_dir = (const float*)d_in[i++];
  const float* proj_err = (const float*)d_in[i++];
  const float* normal   = (const float*)d_in[i++];
  const float* DL       = (const float*)d_in[i++];
  const float* pbr_ln_g = (const float*)d_in[i++];
  const float* pbr_ln_b = (const float*)d_in[i++];
  const float* pbr_w1   = (const float*)d_in[i++];
  const float* pbr_b1   = (const float*)d_in[i++];
  const float* pbr_w2   = (const float*)d_in[i++];
  const float* pbr_b2   = (const float*)d_in[i++];
  const float* pbr_w3   = (const float*)d_in[i++];
  const float* pbr_b3   = (const float*)d_in[i++];
  const float* pbr_w4   = (const float*)d_in[i++];
  const float* pbr_b4   = (const float*)d_in[i++];
  const float* tv1_ln_g = (const float*)d_in[i++];
  const float* tv1_ln_b = (const float*)d_in[i++];
  const float* tv1_w    = (const float*)d_in[i++];
  const float* to1_w    = (const float*)d_in[i++];
  const float* to1_b    = (const float*)d_in[i++];
  const float* n1_ln_g  = (const float*)d_in[i++];
  const float* n1_ln_b  = (const float*)d_in[i++];
  const float* n1_w1    = (const float*)d_in[i++];
  const float* n1_b1    = (const float*)d_in[i++];
  const float* n1_w2    = (const float*)d_in[i++];
  const float* n1_b2    = (const float*)d_in[i++];
  const float* tv2_ln_g = (const float*)d_in[i++];
  const float* tv2_ln_b = (const float*)d_in[i++];
  const float* tv2_w    = (const float*)d_in[i++];
  const float* to2_w    = (const float*)d_in[i++];
  const float* to2_b    = (const float*)d_in[i++];
  const float* n2_ln_g  = (const float*)d_in[i++];
  const float* n2_ln_b  = (const float*)d_in[i++];
  const float* n2_w1    = (const float*)d_in[i++];
  const float* n2_b1    = (const float*)d_in[i++];
  const float* n2_w2    = (const float*)d_in[i++];
  const float* n2_b2    = (const float*)d_in[i++];
  const float* brdf_ln_g= (const float*)d_in[i++];
  const float* brdf_ln_b= (const float*)d_in[i++];
  const float* brdf_w1  = (const float*)d_in[i++];
  const float* brdf_b1  = (const float*)d_in[i++];
  const float* brdf_w2  = (const float*)d_in[i++];
  const float* brdf_b2  = (const float*)d_in[i++];

  float* ws = (float*)d_ws;

  mva_phaseA<<<dim3(NBA), dim3(NTA), 0, stream>>>(
      view_dir, normal, DL, pbr_ln_g, pbr_ln_b,
      pbr_w1, pbr_b1, pbr_w2, pbr_b2, pbr_w3, pbr_b3, pbr_w4, pbr_b4, ws);

  mva_phaseB1<<<dim3(NBB1), dim3(NTB), 0, stream>>>(
      rgb, fm, proj_err, ws,
      tv1_ln_g, tv1_ln_b, tv1_w, to1_w, to1_b,
      n1_ln_g, n1_ln_b, n1_w1, n1_b1, n1_w2, n1_b2,
      tv2_ln_g, tv2_ln_b, tv2_w);

  mva_phaseB2<<<dim3(NBB2), dim3(NTB), 0, stream>>>(
      rgb, fm, ws,
      to2_w, to2_b,
      n2_ln_g, n2_ln_b, n2_w1, n2_b1, n2_w2, n2_b2,
      brdf_ln_g, brdf_ln_b, brdf_w1, brdf_b1, brdf_w2, brdf_b2,
      (float*)d_out);
}